// Round 1
// baseline (46.447 us; speedup 1.0000x reference)
//
#include <hip/hip_runtime.h>
#include <math.h>

// LocalGroupedZernikeNewBP: fused grouped soft-abs + 3x3 box gain + tanh.
// Layout [B=8, H=256, W=256, C=36] fp32, channel-last.
// Groups: special 0..2 (plain tanh), low 3..5, mid 6..14, high 15..35.

static constexpr int IMG_H = 256;
static constexpr int IMG_W = 256;
static constexpr int NBATCH = 8;
static constexpr int CTOT = 36;
static constexpr int TS = 16;  // spatial tile (TS x TS pixels per block, 1 thread/pixel)

__device__ __forceinline__ float fast_tanh(float x) {
    // tanh(x) = 1 - 2/(exp(2x)+1); exp->inf => 1, exp->0 => -1 (saturates correctly)
    float e = __expf(2.0f * x);
    return 1.0f - __fdividef(2.0f, e + 1.0f);
}

__global__ __launch_bounds__(TS * TS) void lgz_kernel(
    const float* __restrict__ in, float* __restrict__ out,
    const float* __restrict__ p_sp_bias, const float* __restrict__ p_sp_alpha,
    const float* __restrict__ p_sp_amax,
    const float* __restrict__ p_lo_bias, const float* __restrict__ p_lo_alpha,
    const float* __restrict__ p_lo_amax, const float* __restrict__ p_lo_eps,
    const float* __restrict__ p_lo_gss, const float* __restrict__ p_lo_psat,
    const float* __restrict__ p_mi_bias, const float* __restrict__ p_mi_alpha,
    const float* __restrict__ p_mi_amax, const float* __restrict__ p_mi_eps,
    const float* __restrict__ p_mi_gss, const float* __restrict__ p_mi_psat,
    const float* __restrict__ p_hi_bias, const float* __restrict__ p_hi_alpha,
    const float* __restrict__ p_hi_amax, const float* __restrict__ p_hi_eps,
    const float* __restrict__ p_hi_gss, const float* __restrict__ p_hi_psat)
{
    __shared__ float s_lo[TS + 2][TS + 2];
    __shared__ float s_mi[TS + 2][TS + 2];
    __shared__ float s_hi[TS + 2][TS + 2];

    const int tx = threadIdx.x, ty = threadIdx.y;
    const int tid = ty * TS + tx;
    const int bx0 = blockIdx.x * TS, by0 = blockIdx.y * TS;
    const int b = blockIdx.z;

    // scalar params (uniform loads)
    const float b_sp = p_sp_bias[0], a_sp = p_sp_alpha[0], m_sp = p_sp_amax[0];
    const float b_lo = p_lo_bias[0], a_lo = p_lo_alpha[0], m_lo = p_lo_amax[0];
    const float e_lo = p_lo_eps[0],  g_lo = p_lo_gss[0],  q_lo = p_lo_psat[0];
    const float b_mi = p_mi_bias[0], a_mi = p_mi_alpha[0], m_mi = p_mi_amax[0];
    const float e_mi = p_mi_eps[0],  g_mi = p_mi_gss[0],  q_mi = p_mi_psat[0];
    const float b_hi = p_hi_bias[0], a_hi = p_hi_alpha[0], m_hi = p_hi_amax[0];
    const float e_hi = p_hi_eps[0],  g_hi = p_hi_gss[0],  q_hi = p_hi_psat[0];

    const float* img = in + (size_t)b * IMG_H * IMG_W * CTOT;
    const int gx = bx0 + tx, gy = by0 + ty;

    // ---- load own pixel: 36 floats = 9 aligned float4 ----
    float v[CTOT];
    {
        const float4* p4 = reinterpret_cast<const float4*>(
            img + ((size_t)gy * IMG_W + gx) * CTOT);
        #pragma unroll
        for (int j = 0; j < 9; ++j) reinterpret_cast<float4*>(v)[j] = p4[j];
    }

    // ---- per-group channel sums of sqrt(u^2+eps) -> LDS interior ----
    float tlo = 0.f, tmi = 0.f, thi = 0.f;
    #pragma unroll
    for (int c = 3; c < 6; ++c)   { float u = v[c] + b_lo; tlo += sqrtf(u * u + e_lo); }
    #pragma unroll
    for (int c = 6; c < 15; ++c)  { float u = v[c] + b_mi; tmi += sqrtf(u * u + e_mi); }
    #pragma unroll
    for (int c = 15; c < 36; ++c) { float u = v[c] + b_hi; thi += sqrtf(u * u + e_hi); }
    s_lo[ty + 1][tx + 1] = tlo;
    s_mi[ty + 1][tx + 1] = tmi;
    s_hi[ty + 1][tx + 1] = thi;

    // ---- halo ring: 2*(TS+2) + 2*TS = 68 pixels, clamped coords (edge pad) ----
    if (tid < 4 * TS + 4) {
        int hy, hx;
        if (tid < TS + 2)                 { hy = 0;                         hx = tid; }
        else if (tid < 2 * (TS + 2))      { hy = TS + 1;                    hx = tid - (TS + 2); }
        else if (tid < 2 * (TS + 2) + TS) { hy = tid - 2 * (TS + 2) + 1;    hx = 0; }
        else                              { hy = tid - (2 * (TS + 2) + TS) + 1; hx = TS + 1; }
        const int gy2 = min(max(by0 + hy - 1, 0), IMG_H - 1);
        const int gx2 = min(max(bx0 + hx - 1, 0), IMG_W - 1);
        const float4* q4 = reinterpret_cast<const float4*>(
            img + ((size_t)gy2 * IMG_W + gx2) * CTOT);
        float w[CTOT];
        #pragma unroll
        for (int j = 0; j < 9; ++j) reinterpret_cast<float4*>(w)[j] = q4[j];
        float hlo = 0.f, hmi = 0.f, hhi = 0.f;
        #pragma unroll
        for (int c = 3; c < 6; ++c)   { float u = w[c] + b_lo; hlo += sqrtf(u * u + e_lo); }
        #pragma unroll
        for (int c = 6; c < 15; ++c)  { float u = w[c] + b_mi; hmi += sqrtf(u * u + e_mi); }
        #pragma unroll
        for (int c = 15; c < 36; ++c) { float u = w[c] + b_hi; hhi += sqrtf(u * u + e_hi); }
        s_lo[hy][hx] = hlo;
        s_mi[hy][hx] = hmi;
        s_hi[hy][hx] = hhi;
    }
    __syncthreads();

    // ---- 3x3 box sums from LDS (window centered at (ty+1, tx+1)) ----
    float slo = 0.f, smi = 0.f, shi = 0.f;
    #pragma unroll
    for (int di = 0; di < 3; ++di) {
        #pragma unroll
        for (int dj = 0; dj < 3; ++dj) {
            slo += s_lo[ty + di][tx + dj];
            smi += s_mi[ty + di][tx + dj];
            shi += s_hi[ty + di][tx + dj];
        }
    }

    // gain = gss / (1 + s/p_sat); fold alpha in
    const float glo = a_lo * __fdividef(g_lo, 1.0f + __fdividef(slo, q_lo));
    const float gmi = a_mi * __fdividef(g_mi, 1.0f + __fdividef(smi, q_mi));
    const float ghi = a_hi * __fdividef(g_hi, 1.0f + __fdividef(shi, q_hi));

    // ---- outputs ----
    float o[CTOT];
    #pragma unroll
    for (int c = 0; c < 3; ++c)   o[c] = m_sp * fast_tanh(a_sp * (v[c] + b_sp));
    #pragma unroll
    for (int c = 3; c < 6; ++c)   o[c] = m_lo * fast_tanh(glo * (v[c] + b_lo));
    #pragma unroll
    for (int c = 6; c < 15; ++c)  o[c] = m_mi * fast_tanh(gmi * (v[c] + b_mi));
    #pragma unroll
    for (int c = 15; c < 36; ++c) o[c] = m_hi * fast_tanh(ghi * (v[c] + b_hi));

    float4* o4 = reinterpret_cast<float4*>(
        out + ((size_t)gy * IMG_W + gx) * CTOT + (size_t)b * IMG_H * IMG_W * CTOT);
    #pragma unroll
    for (int j = 0; j < 9; ++j) o4[j] = reinterpret_cast<const float4*>(o)[j];
}

extern "C" void kernel_launch(void* const* d_in, const int* in_sizes, int n_in,
                              void* d_out, int out_size, void* d_ws, size_t ws_size,
                              hipStream_t stream) {
    const float* raw = (const float*)d_in[0];
    // setup_inputs order:
    // 1:special_bias 2:special_alpha 3:special_amax 4:special_eps(unused)
    // 5:low_bias 6:low_alpha 7:low_amax 8:low_eps 9:low_gss 10:low_p_sat
    // 11:mid_bias 12:mid_alpha 13:mid_amax 14:mid_eps 15:mid_gss 16:mid_p_sat
    // 17:high_bias 18:high_alpha 19:high_amax 20:high_eps 21:high_gss 22:high_p_sat
    dim3 grid(IMG_W / TS, IMG_H / TS, NBATCH);
    dim3 block(TS, TS);
    lgz_kernel<<<grid, block, 0, stream>>>(
        raw, (float*)d_out,
        (const float*)d_in[1], (const float*)d_in[2], (const float*)d_in[3],
        (const float*)d_in[5], (const float*)d_in[6], (const float*)d_in[7],
        (const float*)d_in[8], (const float*)d_in[9], (const float*)d_in[10],
        (const float*)d_in[11], (const float*)d_in[12], (const float*)d_in[13],
        (const float*)d_in[14], (const float*)d_in[15], (const float*)d_in[16],
        (const float*)d_in[17], (const float*)d_in[18], (const float*)d_in[19],
        (const float*)d_in[20], (const float*)d_in[21], (const float*)d_in[22]);
}